// Round 2
// baseline (262.557 us; speedup 1.0000x reference)
//
#include <hip/hip_runtime.h>
#include <hip/hip_bf16.h>

#define B 4096
#define DFEAT 128
#define NCLS 512
#define NEG_INF_F (-1e30f)

typedef __attribute__((ext_vector_type(8))) short bf16x8;
typedef __attribute__((ext_vector_type(4))) float f32x4;

__device__ __forceinline__ unsigned short f2bf(float f) {
    unsigned int u = __float_as_uint(f);
    unsigned int r = (u + 0x7fffu + ((u >> 16) & 1u)) >> 16;
    return (unsigned short)r;
}

// online softmax-weighted accumulation: add one entry with given logit, value d
__device__ __forceinline__ void oupd(float logit, float d, float& m, float& sw, float& swd) {
    if (logit > m) {
        float e = __expf(m - logit);   // m==-1e30 -> e==0 -> resets cleanly
        sw  = fmaf(sw, e, 1.0f);
        swd = fmaf(swd, e, d);
        m = logit;
    } else {
        float e = __expf(logit - m);
        sw += e;
        swd = fmaf(e, d, swd);
    }
}

__device__ __forceinline__ void omerge(float& m, float& sw, float& swd,
                                       float m2, float sw2, float swd2) {
    float M = fmaxf(m, m2);
    float e1 = __expf(m - M);
    float e2 = __expf(m2 - M);
    sw  = sw * e1 + sw2 * e2;
    swd = swd * e1 + swd2 * e2;
    m = M;
}

// reference band logic for a strictly-upper negative pair
__device__ __forceinline__ void neg_update(float d, float mu, float sg, float nz, float st[12]) {
    float obs = fmaf(sg, nz, mu);
    float t1 = fmaf(-2.5f, sg, obs);
    if (d < t1) {
        oupd(10.0f * (t1 - d), d, st[0], st[1], st[2]);
    } else {
        float tm = fmaf(-1.5f, sg, obs);
        if (d < tm) {
            if (d > t1) oupd(5.0f * (tm - d), d, st[3], st[4], st[5]);
        } else {
            float th = fmaf(1.5f, sg, obs);
            if (d < th && d > tm) oupd(5.0f * (th - d), d, st[6], st[7], st[8]);
        }
    }
}

__device__ __forceinline__ void wave_reduce12(float st[12]) {
    #pragma unroll
    for (int off = 32; off; off >>= 1) {
        float o[12];
        #pragma unroll
        for (int k = 0; k < 12; ++k) o[k] = __shfl_down(st[k], off);
        omerge(st[0], st[1], st[2], o[0], o[1], o[2]);
        omerge(st[3], st[4], st[5], o[3], o[4], o[5]);
        omerge(st[6], st[7], st[8], o[6], o[7], o[8]);
        st[9] += o[9]; st[10] += o[10]; st[11] += o[11];
    }
}

// ---------------- kernel 1: x -> bf16 copy + row sum-of-squares ----------------
__global__ void prep_kernel(const float* __restrict__ x,
                            unsigned int* __restrict__ xbf_packed,
                            float* __restrict__ sq) {
    int row = blockIdx.x;
    int lane = threadIdx.x;  // 64
    float2 v = ((const float2*)(x + row * DFEAT))[lane];
    float ss = fmaf(v.x, v.x, v.y * v.y);
    unsigned int pk = ((unsigned int)f2bf(v.y) << 16) | (unsigned int)f2bf(v.x);
    xbf_packed[row * (DFEAT / 2) + lane] = pk;
    #pragma unroll
    for (int off = 32; off; off >>= 1) ss += __shfl_down(ss, off);
    if (lane == 0) sq[row] = ss;
}

// ---------------- kernel 2: fused GEMM -> dist write + streaming loss ----------------
// Tile (by,bx) of 128x128. All tiles write dist. Tiles with bx>=by also run the
// band logic on their strictly-upper pairs directly from accumulator registers:
//  - mean/std gathered per-pair from the L2-resident 1 MiB tables
//  - noise read with the same 64B-segment coalescing as the dist stores
//  - positives (same group i/8 == j/8) only occur on diagonal tiles (128%8==0)
__launch_bounds__(256)
__global__ void fused_kernel(const unsigned short* __restrict__ xbf,
                             const float* __restrict__ sq,
                             const float* __restrict__ noise,
                             const int* __restrict__ y,
                             const float* __restrict__ meant,
                             const float* __restrict__ stdt,
                             float* __restrict__ out,
                             float* __restrict__ partials) {
    const int bx = blockIdx.x;       // col tile
    const int by = blockIdx.y;       // row tile
    const int tid = threadIdx.x;
    const int wave = tid >> 6;
    const int lane = tid & 63;
    const int q = lane >> 4;         // 0..3
    const int l16 = lane & 15;
    const int row0 = by * 128 + (wave >> 1) * 64;
    const int col0 = bx * 128 + (wave & 1) * 64;
    const int blin = by * 32 + bx;

    f32x4 acc[4][4];
    #pragma unroll
    for (int r = 0; r < 4; ++r)
        #pragma unroll
        for (int c = 0; c < 4; ++c)
            acc[r][c] = (f32x4){0.f, 0.f, 0.f, 0.f};

    #pragma unroll
    for (int kk = 0; kk < 4; ++kk) {
        const int ko = kk * 32 + q * 8;
        bf16x8 afr[4], bfr[4];
        #pragma unroll
        for (int r = 0; r < 4; ++r)
            afr[r] = *(const bf16x8*)(xbf + (row0 + r * 16 + l16) * DFEAT + ko);
        #pragma unroll
        for (int c = 0; c < 4; ++c)
            bfr[c] = *(const bf16x8*)(xbf + (col0 + c * 16 + l16) * DFEAT + ko);
        #pragma unroll
        for (int r = 0; r < 4; ++r)
            #pragma unroll
            for (int c = 0; c < 4; ++c)
                acc[r][c] = __builtin_amdgcn_mfma_f32_16x16x32_bf16(afr[r], bfr[c], acc[r][c], 0, 0, 0);
    }

    float sqr[4][4];
    #pragma unroll
    for (int r = 0; r < 4; ++r)
        *(f32x4*)sqr[r] = *(const f32x4*)(sq + row0 + r * 16 + q * 4);
    int cols[4]; float sqc[4];
    #pragma unroll
    for (int c = 0; c < 4; ++c) {
        cols[c] = col0 + c * 16 + l16;
        sqc[c] = sq[cols[c]];
    }

    const bool doLoss = (bx >= by);   // wave-uniform
    const bool diag   = (bx == by);   // wave-uniform

    int yj[4];
    #pragma unroll
    for (int c = 0; c < 4; ++c) yj[c] = doLoss ? y[cols[c]] : 0;

    // st: [0..2]=n1(m,sw,swd) [3..5]=n2 [6..8]=n3 [9..11]=(ps,ps2,cnt)
    float st[12];
    st[0] = st[3] = st[6] = NEG_INF_F;
    st[1] = st[2] = st[4] = st[5] = st[7] = st[8] = st[9] = st[10] = st[11] = 0.f;

    #pragma unroll
    for (int r = 0; r < 4; ++r) {
        #pragma unroll
        for (int t = 0; t < 4; ++t) {
            const int i = row0 + r * 16 + q * 4 + t;
            const size_t base = (size_t)i * B;
            const float si = sqr[r][t];
            const int yi = doLoss ? y[i] : 0;
            #pragma unroll
            for (int c = 0; c < 4; ++c) {
                const int j = cols[c];
                const float d = fmaf(-2.0f, acc[r][c][t], si + sqc[c]);
                out[base + j] = d;
                if (doLoss && (!diag || j > i)) {
                    const int idx = yi * NCLS + yj[c];
                    const float mu = meant[idx];
                    const float sg = stdt[idx];
                    const float nz = noise[base + j];
                    if (diag && (((i ^ j) >> 3) == 0)) {
                        // positive pair (same group, j>i)
                        const float obs = fmaf(sg, nz, mu);
                        const float tp = fmaf(2.0f, sg, obs);
                        if (d > tp) { st[9] += d; st[10] = fmaf(d, d, st[10]); st[11] += 1.0f; }
                    } else {
                        neg_update(d, mu, sg, nz, st);
                    }
                }
            }
        }
    }

    if (!doLoss) {
        if (tid == 0) {
            float* pp = partials + blin * 12;
            pp[0] = pp[3] = pp[6] = NEG_INF_F;
            pp[1] = pp[2] = pp[4] = pp[5] = 0.f;
            pp[7] = pp[8] = pp[9] = pp[10] = pp[11] = 0.f;
        }
        return;
    }

    wave_reduce12(st);

    __shared__ float red[4][12];
    if (lane == 0) {
        #pragma unroll
        for (int k = 0; k < 12; ++k) red[wave][k] = st[k];
    }
    __syncthreads();
    if (tid == 0) {
        float r0[12];
        #pragma unroll
        for (int k = 0; k < 12; ++k) r0[k] = red[0][k];
        #pragma unroll
        for (int w = 1; w < 4; ++w) {
            omerge(r0[0], r0[1], r0[2], red[w][0], red[w][1], red[w][2]);
            omerge(r0[3], r0[4], r0[5], red[w][3], red[w][4], red[w][5]);
            omerge(r0[6], r0[7], r0[8], red[w][6], red[w][7], red[w][8]);
            r0[9] += red[w][9]; r0[10] += red[w][10]; r0[11] += red[w][11];
        }
        float* pp = partials + blin * 12;
        #pragma unroll
        for (int k = 0; k < 12; ++k) pp[k] = r0[k];
    }
}

// ---------------- kernel 3: final reduction + loss ----------------
__global__ void finalize_kernel(const float* __restrict__ partials,
                                float* __restrict__ out) {
    int tid = threadIdx.x;  // 256
    int lane = tid & 63, wave = tid >> 6;
    float st[12];
    st[0] = st[3] = st[6] = NEG_INF_F;
    st[1] = st[2] = st[4] = st[5] = st[7] = st[8] = st[9] = st[10] = st[11] = 0.f;
    for (int p = tid; p < 1024; p += 256) {
        const float* pp = partials + p * 12;
        omerge(st[0], st[1], st[2], pp[0], pp[1], pp[2]);
        omerge(st[3], st[4], st[5], pp[3], pp[4], pp[5]);
        omerge(st[6], st[7], st[8], pp[6], pp[7], pp[8]);
        st[9] += pp[9]; st[10] += pp[10]; st[11] += pp[11];
    }
    wave_reduce12(st);
    __shared__ float red[4][12];
    if (lane == 0) {
        #pragma unroll
        for (int k = 0; k < 12; ++k) red[wave][k] = st[k];
    }
    __syncthreads();
    if (tid == 0) {
        float r0[12];
        #pragma unroll
        for (int k = 0; k < 12; ++k) r0[k] = red[0][k];
        #pragma unroll
        for (int w = 1; w < 4; ++w) {
            omerge(r0[0], r0[1], r0[2], red[w][0], red[w][1], red[w][2]);
            omerge(r0[3], r0[4], r0[5], red[w][3], red[w][4], red[w][5]);
            omerge(r0[6], r0[7], r0[8], red[w][6], red[w][7], red[w][8]);
            r0[9] += red[w][9]; r0[10] += red[w][10]; r0[11] += red[w][11];
        }
        float ln1 = (r0[1] > 0.f) ? -(r0[2] / r0[1]) : -0.0001f;
        float ln2 = (r0[4] > 0.f) ? -(r0[5] / r0[4]) : -0.0001f;
        float ln3 = (r0[7] > 0.f) ? -(r0[8] / r0[7]) : -0.0001f;
        float lp  = (r0[11] > 0.f) ? (r0[10] / ((r0[9] != 0.f) ? r0[9] : 1.f)) : 0.0001f;
        out[(size_t)B * B] = 1.0f + 0.25f * (ln1 + ln2 + ln3 + lp);
    }
}

extern "C" void kernel_launch(void* const* d_in, const int* in_sizes, int n_in,
                              void* d_out, int out_size, void* d_ws, size_t ws_size,
                              hipStream_t stream) {
    const float* x     = (const float*)d_in[0];
    const int*   y     = (const int*)d_in[1];
    const float* meant = (const float*)d_in[2];
    const float* stdt  = (const float*)d_in[3];
    const float* noise = (const float*)d_in[4];
    float* out = (float*)d_out;
    char* ws = (char*)d_ws;
    unsigned short* xbf = (unsigned short*)ws;            // 1 MiB
    float* sq           = (float*)(ws + 1048576);         // 16 KiB
    float* partials     = (float*)(ws + 1064960);         // 1024*12*4 = 48 KiB

    hipLaunchKernelGGL(prep_kernel, dim3(B), dim3(64), 0, stream,
                       x, (unsigned int*)xbf, sq);
    hipLaunchKernelGGL(fused_kernel, dim3(32, 32), dim3(256), 0, stream,
                       xbf, sq, noise, y, meant, stdt, out, partials);
    hipLaunchKernelGGL(finalize_kernel, dim3(1), dim3(256), 0, stream,
                       partials, out);
}

// Round 3
// 247.267 us; speedup vs baseline: 1.0618x; 1.0618x over previous
//
#include <hip/hip_runtime.h>
#include <hip/hip_bf16.h>

#define B 4096
#define DFEAT 128
#define NCLS 512
#define NEG_INF_F (-1e30f)

typedef __attribute__((ext_vector_type(8))) short bf16x8;
typedef __attribute__((ext_vector_type(4))) float f32x4;

__device__ __forceinline__ unsigned short f2bf(float f) {
    unsigned int u = __float_as_uint(f);
    unsigned int r = (u + 0x7fffu + ((u >> 16) & 1u)) >> 16;
    return (unsigned short)r;
}

// online softmax-weighted accumulation: add one entry with given logit, value d
__device__ __forceinline__ void oupd(float logit, float d, float& m, float& sw, float& swd) {
    if (logit > m) {
        float e = __expf(m - logit);   // m==-1e30 -> e==0 -> resets cleanly
        sw  = fmaf(sw, e, 1.0f);
        swd = fmaf(swd, e, d);
        m = logit;
    } else {
        float e = __expf(logit - m);
        sw += e;
        swd = fmaf(e, d, swd);
    }
}

__device__ __forceinline__ void omerge(float& m, float& sw, float& swd,
                                       float m2, float sw2, float swd2) {
    float M = fmaxf(m, m2);
    float e1 = __expf(m - M);
    float e2 = __expf(m2 - M);
    sw  = sw * e1 + sw2 * e2;
    swd = swd * e1 + swd2 * e2;
    m = M;
}

// reference band logic for a strictly-upper negative pair
__device__ __forceinline__ void neg_update(float d, float mu, float sg, float nz, float st[12]) {
    float obs = fmaf(sg, nz, mu);
    float t1 = fmaf(-2.5f, sg, obs);
    if (d < t1) {
        oupd(10.0f * (t1 - d), d, st[0], st[1], st[2]);
    } else {
        float tm = fmaf(-1.5f, sg, obs);
        if (d < tm) {
            if (d > t1) oupd(5.0f * (tm - d), d, st[3], st[4], st[5]);
        } else {
            float th = fmaf(1.5f, sg, obs);
            if (d < th && d > tm) oupd(5.0f * (th - d), d, st[6], st[7], st[8]);
        }
    }
}

__device__ __forceinline__ void wave_reduce12(float st[12]) {
    #pragma unroll
    for (int off = 32; off; off >>= 1) {
        float o[12];
        #pragma unroll
        for (int k = 0; k < 12; ++k) o[k] = __shfl_down(st[k], off);
        omerge(st[0], st[1], st[2], o[0], o[1], o[2]);
        omerge(st[3], st[4], st[5], o[3], o[4], o[5]);
        omerge(st[6], st[7], st[8], o[6], o[7], o[8]);
        st[9] += o[9]; st[10] += o[10]; st[11] += o[11];
    }
}

// ---------------- kernel 1: x -> bf16 copy + row sum-of-squares ----------------
__global__ void prep_kernel(const float* __restrict__ x,
                            unsigned int* __restrict__ xbf_packed,
                            float* __restrict__ sq) {
    int row = blockIdx.x;
    int lane = threadIdx.x;  // 64
    float2 v = ((const float2*)(x + row * DFEAT))[lane];
    float ss = fmaf(v.x, v.x, v.y * v.y);
    unsigned int pk = ((unsigned int)f2bf(v.y) << 16) | (unsigned int)f2bf(v.x);
    xbf_packed[row * (DFEAT / 2) + lane] = pk;
    #pragma unroll
    for (int off = 32; off; off >>= 1) ss += __shfl_down(ss, off);
    if (lane == 0) sq[row] = ss;
}

// ---------------- kernel 2: fused GEMM -> dist write + balanced streaming loss ----------
// Tile (by,bx) of 128x128. All tiles write dist. Loss work is mirror-split:
//   upper blocks (by<bx): pairs with (r+c) even (local layout)
//   lower blocks (by>bx): complementary pairs, (r+c) odd, via transposed access
//     (same pair sits at subtile (c,r) in the mirror block -> same parity, so
//      even/odd split is exactly complementary). Transposed noise reads become
//      fully-coalesced float4 loads.
//   diagonal blocks: all j>i pairs, predicated updates, unconditional loads.
// All loads batched per 16x16 subtile (compile-time indices, branch-free) for MLP.
__launch_bounds__(256)
__global__ void fused_kernel(const unsigned short* __restrict__ xbf,
                             const float* __restrict__ sq,
                             const float* __restrict__ noise,
                             const int* __restrict__ y,
                             const float* __restrict__ meant,
                             const float* __restrict__ stdt,
                             float* __restrict__ out,
                             float* __restrict__ partials) {
    const int bx = blockIdx.x;       // col tile
    const int by = blockIdx.y;       // row tile
    const int tid = threadIdx.x;
    const int wave = tid >> 6;
    const int lane = tid & 63;
    const int q = lane >> 4;         // 0..3
    const int l16 = lane & 15;
    const int row0 = by * 128 + (wave >> 1) * 64;
    const int col0 = bx * 128 + (wave & 1) * 64;
    const int blin = by * 32 + bx;

    f32x4 acc[4][4];
    #pragma unroll
    for (int r = 0; r < 4; ++r)
        #pragma unroll
        for (int c = 0; c < 4; ++c)
            acc[r][c] = (f32x4){0.f, 0.f, 0.f, 0.f};

    #pragma unroll
    for (int kk = 0; kk < 4; ++kk) {
        const int ko = kk * 32 + q * 8;
        bf16x8 afr[4], bfr[4];
        #pragma unroll
        for (int r = 0; r < 4; ++r)
            afr[r] = *(const bf16x8*)(xbf + (row0 + r * 16 + l16) * DFEAT + ko);
        #pragma unroll
        for (int c = 0; c < 4; ++c)
            bfr[c] = *(const bf16x8*)(xbf + (col0 + c * 16 + l16) * DFEAT + ko);
        #pragma unroll
        for (int r = 0; r < 4; ++r)
            #pragma unroll
            for (int c = 0; c < 4; ++c)
                acc[r][c] = __builtin_amdgcn_mfma_f32_16x16x32_bf16(afr[r], bfr[c], acc[r][c], 0, 0, 0);
    }

    float sqr[4][4];
    #pragma unroll
    for (int r = 0; r < 4; ++r)
        *(f32x4*)sqr[r] = *(const f32x4*)(sq + row0 + r * 16 + q * 4);
    int cols[4]; float sqc[4];
    #pragma unroll
    for (int c = 0; c < 4; ++c) {
        cols[c] = col0 + c * 16 + l16;
        sqc[c] = sq[cols[c]];
    }

    // ---- dist store (all blocks) ----
    #pragma unroll
    for (int r = 0; r < 4; ++r) {
        #pragma unroll
        for (int t = 0; t < 4; ++t) {
            const size_t base = (size_t)(row0 + r * 16 + q * 4 + t) * B;
            const float s = sqr[r][t];
            #pragma unroll
            for (int c = 0; c < 4; ++c)
                out[base + cols[c]] = fmaf(-2.0f, acc[r][c][t], s + sqc[c]);
        }
    }

    // ---- loss phase (all blocks, balanced) ----
    int yrow[4][4];
    #pragma unroll
    for (int r = 0; r < 4; ++r)
        *(int4*)yrow[r] = *(const int4*)(y + row0 + r * 16 + q * 4);
    int ycol[4];
    #pragma unroll
    for (int c = 0; c < 4; ++c) ycol[c] = y[cols[c]];

    // st: [0..2]=n1(m,sw,swd) [3..5]=n2 [6..8]=n3 [9..11]=(ps,ps2,cnt)
    float st[12];
    st[0] = st[3] = st[6] = NEG_INF_F;
    st[1] = st[2] = st[4] = st[5] = st[7] = st[8] = st[9] = st[10] = st[11] = 0.f;

    if (by < bx) {
        // pure-upper tile: take (r+c) even pairs, row-major noise
        #pragma unroll
        for (int r = 0; r < 4; ++r) {
            #pragma unroll
            for (int c = 0; c < 4; ++c) {
                if (((r + c) & 1) != 0) continue;   // compile-time
                float mu_[4], sg_[4], nz_[4];
                #pragma unroll
                for (int t = 0; t < 4; ++t) {
                    const int idx = yrow[r][t] * NCLS + ycol[c];
                    mu_[t] = meant[idx];
                    sg_[t] = stdt[idx];
                    nz_[t] = noise[(size_t)(row0 + r * 16 + q * 4 + t) * B + cols[c]];
                }
                #pragma unroll
                for (int t = 0; t < 4; ++t) {
                    const float d = fmaf(-2.0f, acc[r][c][t], sqr[r][t] + sqc[c]);
                    neg_update(d, mu_[t], sg_[t], nz_[t], st);
                }
            }
        }
    } else if (by > bx) {
        // mirror of an upper tile: take (r+c) odd pairs; global pair is (j_local, i_local)
        // -> idx = y[col]*NCLS + y[row]; noise[col*B + row] = coalesced float4 over t
        #pragma unroll
        for (int r = 0; r < 4; ++r) {
            #pragma unroll
            for (int c = 0; c < 4; ++c) {
                if (((r + c) & 1) != 1) continue;   // compile-time
                const float4 nz4 = *(const float4*)(noise + (size_t)cols[c] * B + row0 + r * 16 + q * 4);
                float mu_[4], sg_[4];
                #pragma unroll
                for (int t = 0; t < 4; ++t) {
                    const int idx = ycol[c] * NCLS + yrow[r][t];
                    mu_[t] = meant[idx];
                    sg_[t] = stdt[idx];
                }
                const float nzv[4] = {nz4.x, nz4.y, nz4.z, nz4.w};
                #pragma unroll
                for (int t = 0; t < 4; ++t) {
                    const float d = fmaf(-2.0f, acc[r][c][t], sqr[r][t] + sqc[c]);
                    neg_update(d, mu_[t], sg_[t], nzv[t], st);
                }
            }
        }
    } else {
        // diagonal tile: all strictly-upper pairs of this tile; loads unconditional,
        // updates predicated. Positives (same group of 8) occur only here.
        #pragma unroll
        for (int r = 0; r < 4; ++r) {
            #pragma unroll
            for (int c = 0; c < 4; ++c) {
                float mu_[4], sg_[4], nz_[4];
                #pragma unroll
                for (int t = 0; t < 4; ++t) {
                    const int idx = yrow[r][t] * NCLS + ycol[c];
                    mu_[t] = meant[idx];
                    sg_[t] = stdt[idx];
                    nz_[t] = noise[(size_t)(row0 + r * 16 + q * 4 + t) * B + cols[c]];
                }
                #pragma unroll
                for (int t = 0; t < 4; ++t) {
                    const int i = row0 + r * 16 + q * 4 + t;
                    const int j = cols[c];
                    if (j > i) {
                        const float d = fmaf(-2.0f, acc[r][c][t], sqr[r][t] + sqc[c]);
                        if (((i ^ j) >> 3) == 0) {
                            const float obs = fmaf(sg_[t], nz_[t], mu_[t]);
                            const float tp = fmaf(2.0f, sg_[t], obs);
                            if (d > tp) { st[9] += d; st[10] = fmaf(d, d, st[10]); st[11] += 1.0f; }
                        } else {
                            neg_update(d, mu_[t], sg_[t], nz_[t], st);
                        }
                    }
                }
            }
        }
    }

    wave_reduce12(st);

    __shared__ float red[4][12];
    if (lane == 0) {
        #pragma unroll
        for (int k = 0; k < 12; ++k) red[wave][k] = st[k];
    }
    __syncthreads();
    if (tid == 0) {
        float r0[12];
        #pragma unroll
        for (int k = 0; k < 12; ++k) r0[k] = red[0][k];
        #pragma unroll
        for (int w = 1; w < 4; ++w) {
            omerge(r0[0], r0[1], r0[2], red[w][0], red[w][1], red[w][2]);
            omerge(r0[3], r0[4], r0[5], red[w][3], red[w][4], red[w][5]);
            omerge(r0[6], r0[7], r0[8], red[w][6], red[w][7], red[w][8]);
            r0[9] += red[w][9]; r0[10] += red[w][10]; r0[11] += red[w][11];
        }
        float* pp = partials + blin * 12;
        #pragma unroll
        for (int k = 0; k < 12; ++k) pp[k] = r0[k];
    }
}

// ---------------- kernel 3: final reduction + loss ----------------
__global__ void finalize_kernel(const float* __restrict__ partials,
                                float* __restrict__ out) {
    int tid = threadIdx.x;  // 256
    int lane = tid & 63, wave = tid >> 6;
    float st[12];
    st[0] = st[3] = st[6] = NEG_INF_F;
    st[1] = st[2] = st[4] = st[5] = st[7] = st[8] = st[9] = st[10] = st[11] = 0.f;
    for (int p = tid; p < 1024; p += 256) {
        const float* pp = partials + p * 12;
        omerge(st[0], st[1], st[2], pp[0], pp[1], pp[2]);
        omerge(st[3], st[4], st[5], pp[3], pp[4], pp[5]);
        omerge(st[6], st[7], st[8], pp[6], pp[7], pp[8]);
        st[9] += pp[9]; st[10] += pp[10]; st[11] += pp[11];
    }
    wave_reduce12(st);
    __shared__ float red[4][12];
    if (lane == 0) {
        #pragma unroll
        for (int k = 0; k < 12; ++k) red[wave][k] = st[k];
    }
    __syncthreads();
    if (tid == 0) {
        float r0[12];
        #pragma unroll
        for (int k = 0; k < 12; ++k) r0[k] = red[0][k];
        #pragma unroll
        for (int w = 1; w < 4; ++w) {
            omerge(r0[0], r0[1], r0[2], red[w][0], red[w][1], red[w][2]);
            omerge(r0[3], r0[4], r0[5], red[w][3], red[w][4], red[w][5]);
            omerge(r0[6], r0[7], r0[8], red[w][6], red[w][7], red[w][8]);
            r0[9] += red[w][9]; r0[10] += red[w][10]; r0[11] += red[w][11];
        }
        float ln1 = (r0[1] > 0.f) ? -(r0[2] / r0[1]) : -0.0001f;
        float ln2 = (r0[4] > 0.f) ? -(r0[5] / r0[4]) : -0.0001f;
        float ln3 = (r0[7] > 0.f) ? -(r0[8] / r0[7]) : -0.0001f;
        float lp  = (r0[11] > 0.f) ? (r0[10] / ((r0[9] != 0.f) ? r0[9] : 1.f)) : 0.0001f;
        out[(size_t)B * B] = 1.0f + 0.25f * (ln1 + ln2 + ln3 + lp);
    }
}

extern "C" void kernel_launch(void* const* d_in, const int* in_sizes, int n_in,
                              void* d_out, int out_size, void* d_ws, size_t ws_size,
                              hipStream_t stream) {
    const float* x     = (const float*)d_in[0];
    const int*   y     = (const int*)d_in[1];
    const float* meant = (const float*)d_in[2];
    const float* stdt  = (const float*)d_in[3];
    const float* noise = (const float*)d_in[4];
    float* out = (float*)d_out;
    char* ws = (char*)d_ws;
    unsigned short* xbf = (unsigned short*)ws;            // 1 MiB
    float* sq           = (float*)(ws + 1048576);         // 16 KiB
    float* partials     = (float*)(ws + 1064960);         // 1024*12*4 = 48 KiB

    hipLaunchKernelGGL(prep_kernel, dim3(B), dim3(64), 0, stream,
                       x, (unsigned int*)xbf, sq);
    hipLaunchKernelGGL(fused_kernel, dim3(32, 32), dim3(256), 0, stream,
                       xbf, sq, noise, y, meant, stdt, out, partials);
    hipLaunchKernelGGL(finalize_kernel, dim3(1), dim3(256), 0, stream,
                       partials, out);
}

// Round 4
// 204.632 us; speedup vs baseline: 1.2831x; 1.2083x over previous
//
#include <hip/hip_runtime.h>
#include <hip/hip_bf16.h>

#define B 4096
#define DFEAT 128
#define NCLS 512
#define NEG_INF_F (-1e30f)

typedef __attribute__((ext_vector_type(8))) short bf16x8;
typedef __attribute__((ext_vector_type(4))) float f32x4;

__device__ __forceinline__ unsigned short f2bf(float f) {
    unsigned int u = __float_as_uint(f);
    unsigned int r = (u + 0x7fffu + ((u >> 16) & 1u)) >> 16;
    return (unsigned short)r;
}

__device__ __forceinline__ void oupd(float logit, float d, float& m, float& sw, float& swd) {
    if (logit > m) {
        float e = __expf(m - logit);   // m==-1e30 -> e==0 -> resets cleanly
        sw  = fmaf(sw, e, 1.0f);
        swd = fmaf(swd, e, d);
        m = logit;
    } else {
        float e = __expf(logit - m);
        sw += e;
        swd = fmaf(e, d, swd);
    }
}

__device__ __forceinline__ void omerge(float& m, float& sw, float& swd,
                                       float m2, float sw2, float swd2) {
    float M = fmaxf(m, m2);
    float e1 = __expf(m - M);
    float e2 = __expf(m2 - M);
    sw  = sw * e1 + sw2 * e2;
    swd = swd * e1 + swd2 * e2;
    m = M;
}

__device__ __forceinline__ void neg_update(float d, float mu, float sg, float nz, float st[12]) {
    float obs = fmaf(sg, nz, mu);
    float t1 = fmaf(-2.5f, sg, obs);
    if (d < t1) {
        oupd(10.0f * (t1 - d), d, st[0], st[1], st[2]);
    } else {
        float tm = fmaf(-1.5f, sg, obs);
        if (d < tm) {
            if (d > t1) oupd(5.0f * (tm - d), d, st[3], st[4], st[5]);
        } else {
            float th = fmaf(1.5f, sg, obs);
            if (d < th && d > tm) oupd(5.0f * (th - d), d, st[6], st[7], st[8]);
        }
    }
}

__device__ __forceinline__ void wave_reduce12(float st[12]) {
    #pragma unroll
    for (int off = 32; off; off >>= 1) {
        float o[12];
        #pragma unroll
        for (int k = 0; k < 12; ++k) o[k] = __shfl_down(st[k], off);
        omerge(st[0], st[1], st[2], o[0], o[1], o[2]);
        omerge(st[3], st[4], st[5], o[3], o[4], o[5]);
        omerge(st[6], st[7], st[8], o[6], o[7], o[8]);
        st[9] += o[9]; st[10] += o[10]; st[11] += o[11];
    }
}

// ---------------- kernel 1: x -> bf16 copy + row sum-of-squares ----------------
__global__ void prep_kernel(const float* __restrict__ x,
                            unsigned int* __restrict__ xbf_packed,
                            float* __restrict__ sq) {
    int row = blockIdx.x;
    int lane = threadIdx.x;  // 64
    float2 v = ((const float2*)(x + row * DFEAT))[lane];
    float ss = fmaf(v.x, v.x, v.y * v.y);
    unsigned int pk = ((unsigned int)f2bf(v.y) << 16) | (unsigned int)f2bf(v.x);
    xbf_packed[row * (DFEAT / 2) + lane] = pk;
    #pragma unroll
    for (int off = 32; off; off >>= 1) ss += __shfl_down(ss, off);
    if (lane == 0) sq[row] = ss;
}

// ---------------- kernel 2: row-strip fused GEMM + dist write + loss ----------------
// Block bid = (sp, ph): two 4-row strips (rows 4sp.. and 4(1023-sp)..) x half the
// 16-col tiles (tile index == ph mod 2). Only 8 distinct y[i] per block -> the
// (mu,sg) table rows are staged interleaved in 32 KB LDS; all per-pair table
// lookups are single ds_read_b64. MFMA uses rows 0..7 of a 16x16 tile (pad);
// a __shfl half-combine packs two tiles' valid rows into all 64 lanes so the
// epilogue (store + band logic) has no idle lanes. Strip pairing + phase
// interleave balances loss work exactly across the 1024 blocks.
__launch_bounds__(256)
__global__ void fused_kernel(const unsigned short* __restrict__ xbf,
                             const float* __restrict__ sq,
                             const float* __restrict__ noise,
                             const int* __restrict__ y,
                             const float* __restrict__ meant,
                             const float* __restrict__ stdt,
                             float* __restrict__ out,
                             float* __restrict__ partials) {
    const int bid = blockIdx.x;        // 0..1023
    const int sp  = bid >> 1;          // strip pair 0..511
    const int ph  = bid & 1;           // column phase
    const int tid = threadIdx.x;
    const int wave = tid >> 6;
    const int lane = tid & 63;
    const int q   = lane >> 4;         // 0..3
    const int l16 = lane & 15;
    const int half = lane >> 5;        // 0: tile T0, 1: tile T1
    const int rowA0 = sp * 4;
    const int rowB0 = (1023 - sp) * 4;

    // ---- stage (mu,sg) rows for the block's 8 rows into LDS ----
    __shared__ float2 musg[8][NCLS];   // 32 KB
    #pragma unroll
    for (int r = 0; r < 8; ++r) {
        const int gi = (r < 4) ? (rowA0 + r) : (rowB0 + r - 4);
        const int yr = y[gi];
        for (int c = tid; c < NCLS; c += 256)
            musg[r][c] = make_float2(meant[yr * NCLS + c], stdt[yr * NCLS + c]);
    }
    __syncthreads();

    // ---- A fragment: 16 rows = stripA(4) + stripB(4) + pad(8, repeat) ----
    const int arow = (l16 < 4) ? (rowA0 + l16)
                   : (l16 < 8) ? (rowB0 + l16 - 4)
                               : ((l16 & 4) ? (rowB0 + (l16 & 3)) : (rowA0 + (l16 & 3)));
    bf16x8 afr[4];
    #pragma unroll
    for (int kk = 0; kk < 4; ++kk)
        afr[kk] = *(const bf16x8*)(xbf + arow * DFEAT + kk * 32 + q * 8);

    // per-lane row info for the epilogue: m = (q&1)*4 + t
    const int ibase = (q & 1) ? rowB0 : rowA0;
    const int mbase = (q & 1) * 4;
    const f32x4 sqi = *(const f32x4*)(sq + ibase);

    // st: [0..2]=n1(m,sw,swd) [3..5]=n2 [6..8]=n3 [9..11]=(ps,ps2,cnt)
    float st[12];
    st[0] = st[3] = st[6] = NEG_INF_F;
    st[1] = st[2] = st[4] = st[5] = st[7] = st[8] = st[9] = st[10] = st[11] = 0.f;

    // ---- main loop: 32 tiles per wave, processed in pairs ----
    for (int v = 0; v < 32; v += 2) {
        const int T0 = ph + 2 * (wave + 4 * v);
        const int T1 = ph + 2 * (wave + 4 * (v + 1));
        const int j0a = T0 * 16;
        const int j0b = T1 * 16;          // = j0a + 128

        bf16x8 b0[4], b1[4];
        #pragma unroll
        for (int kk = 0; kk < 4; ++kk) {
            b0[kk] = *(const bf16x8*)(xbf + (j0a + l16) * DFEAT + kk * 32 + q * 8);
            b1[kk] = *(const bf16x8*)(xbf + (j0b + l16) * DFEAT + kk * 32 + q * 8);
        }
        f32x4 a0 = (f32x4){0.f, 0.f, 0.f, 0.f};
        f32x4 a1 = (f32x4){0.f, 0.f, 0.f, 0.f};
        #pragma unroll
        for (int kk = 0; kk < 4; ++kk) {
            a0 = __builtin_amdgcn_mfma_f32_16x16x32_bf16(afr[kk], b0[kk], a0, 0, 0, 0);
            a1 = __builtin_amdgcn_mfma_f32_16x16x32_bf16(afr[kk], b1[kk], a1, 0, 0, 0);
        }

        // combine: lanes<32 keep tile T0 (rows 0..7); lanes>=32 take tile T1 rows 0..7
        f32x4 comb;
        #pragma unroll
        for (int t = 0; t < 4; ++t) {
            const float sh = __shfl(a1[t], lane & 31);
            comb[t] = half ? sh : a0[t];
        }

        const int jcol = (half ? j0b : j0a) + l16;
        const float sqc = sq[jcol];
        const int yj = y[jcol];

        // dist store (all pairs)
        float dv[4];
        #pragma unroll
        for (int t = 0; t < 4; ++t) {
            const int i = ibase + t;
            dv[t] = fmaf(-2.0f, comb[t], sqi[t] + sqc);
            out[(size_t)i * B + jcol] = dv[t];
        }

        // loss (upper-triangle pairs only); uniform skip when both tiles are
        // entirely at/below the diagonal of the lower strip
        if (j0b + 15 > rowA0) {
            float2 ms[4]; float nz[4];
            #pragma unroll
            for (int t = 0; t < 4; ++t)
                ms[t] = musg[mbase + t][yj];
            #pragma unroll
            for (int t = 0; t < 4; ++t) {
                const int i = ibase + t;
                nz[t] = (jcol > i) ? noise[(size_t)i * B + jcol] : 0.f;
            }
            #pragma unroll
            for (int t = 0; t < 4; ++t) {
                const int i = ibase + t;
                if (jcol > i) {
                    if (((i ^ jcol) >> 3) == 0) {
                        // positive pair (same group of 8)
                        const float obs = fmaf(ms[t].y, nz[t], ms[t].x);
                        const float tp = fmaf(2.0f, ms[t].y, obs);
                        if (dv[t] > tp) { st[9] += dv[t]; st[10] = fmaf(dv[t], dv[t], st[10]); st[11] += 1.0f; }
                    } else {
                        neg_update(dv[t], ms[t].x, ms[t].y, nz[t], st);
                    }
                }
            }
        }
    }

    wave_reduce12(st);

    __shared__ float red[4][12];
    if (lane == 0) {
        #pragma unroll
        for (int k = 0; k < 12; ++k) red[wave][k] = st[k];
    }
    __syncthreads();
    if (tid == 0) {
        float r0[12];
        #pragma unroll
        for (int k = 0; k < 12; ++k) r0[k] = red[0][k];
        #pragma unroll
        for (int w = 1; w < 4; ++w) {
            omerge(r0[0], r0[1], r0[2], red[w][0], red[w][1], red[w][2]);
            omerge(r0[3], r0[4], r0[5], red[w][3], red[w][4], red[w][5]);
            omerge(r0[6], r0[7], r0[8], red[w][6], red[w][7], red[w][8]);
            r0[9] += red[w][9]; r0[10] += red[w][10]; r0[11] += red[w][11];
        }
        float* pp = partials + bid * 12;
        #pragma unroll
        for (int k = 0; k < 12; ++k) pp[k] = r0[k];
    }
}

// ---------------- kernel 3: final reduction + loss ----------------
__global__ void finalize_kernel(const float* __restrict__ partials,
                                float* __restrict__ out) {
    int tid = threadIdx.x;  // 256
    int lane = tid & 63, wave = tid >> 6;
    float st[12];
    st[0] = st[3] = st[6] = NEG_INF_F;
    st[1] = st[2] = st[4] = st[5] = st[7] = st[8] = st[9] = st[10] = st[11] = 0.f;
    for (int p = tid; p < 1024; p += 256) {
        const float* pp = partials + p * 12;
        omerge(st[0], st[1], st[2], pp[0], pp[1], pp[2]);
        omerge(st[3], st[4], st[5], pp[3], pp[4], pp[5]);
        omerge(st[6], st[7], st[8], pp[6], pp[7], pp[8]);
        st[9] += pp[9]; st[10] += pp[10]; st[11] += pp[11];
    }
    wave_reduce12(st);
    __shared__ float red[4][12];
    if (lane == 0) {
        #pragma unroll
        for (int k = 0; k < 12; ++k) red[wave][k] = st[k];
    }
    __syncthreads();
    if (tid == 0) {
        float r0[12];
        #pragma unroll
        for (int k = 0; k < 12; ++k) r0[k] = red[0][k];
        #pragma unroll
        for (int w = 1; w < 4; ++w) {
            omerge(r0[0], r0[1], r0[2], red[w][0], red[w][1], red[w][2]);
            omerge(r0[3], r0[4], r0[5], red[w][3], red[w][4], red[w][5]);
            omerge(r0[6], r0[7], r0[8], red[w][6], red[w][7], red[w][8]);
            r0[9] += red[w][9]; r0[10] += red[w][10]; r0[11] += red[w][11];
        }
        float ln1 = (r0[1] > 0.f) ? -(r0[2] / r0[1]) : -0.0001f;
        float ln2 = (r0[4] > 0.f) ? -(r0[5] / r0[4]) : -0.0001f;
        float ln3 = (r0[7] > 0.f) ? -(r0[8] / r0[7]) : -0.0001f;
        float lp  = (r0[11] > 0.f) ? (r0[10] / ((r0[9] != 0.f) ? r0[9] : 1.f)) : 0.0001f;
        out[(size_t)B * B] = 1.0f + 0.25f * (ln1 + ln2 + ln3 + lp);
    }
}

extern "C" void kernel_launch(void* const* d_in, const int* in_sizes, int n_in,
                              void* d_out, int out_size, void* d_ws, size_t ws_size,
                              hipStream_t stream) {
    const float* x     = (const float*)d_in[0];
    const int*   y     = (const int*)d_in[1];
    const float* meant = (const float*)d_in[2];
    const float* stdt  = (const float*)d_in[3];
    const float* noise = (const float*)d_in[4];
    float* out = (float*)d_out;
    char* ws = (char*)d_ws;
    unsigned short* xbf = (unsigned short*)ws;            // 1 MiB
    float* sq           = (float*)(ws + 1048576);         // 16 KiB
    float* partials     = (float*)(ws + 1064960);         // 1024*12*4 = 48 KiB

    hipLaunchKernelGGL(prep_kernel, dim3(B), dim3(64), 0, stream,
                       x, (unsigned int*)xbf, sq);
    hipLaunchKernelGGL(fused_kernel, dim3(1024), dim3(256), 0, stream,
                       xbf, sq, noise, y, meant, stdt, out, partials);
    hipLaunchKernelGGL(finalize_kernel, dim3(1), dim3(256), 0, stream,
                       partials, out);
}

// Round 5
// 201.319 us; speedup vs baseline: 1.3042x; 1.0165x over previous
//
#include <hip/hip_runtime.h>
#include <hip/hip_bf16.h>

#define B 4096
#define DFEAT 128
#define NCLS 512
#define NEG_INF_F (-1e30f)
#define SKIP_F (-2e30f)   // skip sentinel: < NEG_INF_F, exp(SKIP-m)==0 always

typedef __attribute__((ext_vector_type(8))) short bf16x8;
typedef __attribute__((ext_vector_type(4))) float f32x4;

__device__ __forceinline__ unsigned short f2bf(float f) {
    unsigned int u = __float_as_uint(f);
    unsigned int r = (u + 0x7fffu + ((u >> 16) & 1u)) >> 16;
    return (unsigned short)r;
}

// online softmax-weighted accumulation. logit==SKIP_F is a provable no-op:
// SKIP_F > m never holds (m >= -1e30), and exp(SKIP_F - m) == 0.
__device__ __forceinline__ void oupd(float logit, float d, float& m, float& sw, float& swd) {
    if (logit > m) {
        float e = __expf(m - logit);   // m==-1e30 -> e==0 -> resets cleanly
        sw  = fmaf(sw, e, 1.0f);
        swd = fmaf(swd, e, d);
        m = logit;
    } else {
        float e = __expf(logit - m);
        sw += e;
        swd = fmaf(e, d, swd);
    }
}

__device__ __forceinline__ void omerge(float& m, float& sw, float& swd,
                                       float m2, float sw2, float swd2) {
    float M = fmaxf(m, m2);
    float e1 = __expf(m - M);
    float e2 = __expf(m2 - M);
    sw  = sw * e1 + sw2 * e2;
    swd = swd * e1 + swd2 * e2;
    m = M;
}

__device__ __forceinline__ void wave_reduce12(float st[12]) {
    #pragma unroll
    for (int off = 32; off; off >>= 1) {
        float o[12];
        #pragma unroll
        for (int k = 0; k < 12; ++k) o[k] = __shfl_down(st[k], off);
        omerge(st[0], st[1], st[2], o[0], o[1], o[2]);
        omerge(st[3], st[4], st[5], o[3], o[4], o[5]);
        omerge(st[6], st[7], st[8], o[6], o[7], o[8]);
        st[9] += o[9]; st[10] += o[10]; st[11] += o[11];
    }
}

// ---------------- kernel 1: x -> bf16 copy + row sum-of-squares ----------------
__global__ void prep_kernel(const float* __restrict__ x,
                            unsigned int* __restrict__ xbf_packed,
                            float* __restrict__ sq) {
    int row = blockIdx.x;
    int lane = threadIdx.x;  // 64
    float2 v = ((const float2*)(x + row * DFEAT))[lane];
    float ss = fmaf(v.x, v.x, v.y * v.y);
    unsigned int pk = ((unsigned int)f2bf(v.y) << 16) | (unsigned int)f2bf(v.x);
    xbf_packed[row * (DFEAT / 2) + lane] = pk;
    #pragma unroll
    for (int off = 32; off; off >>= 1) ss += __shfl_down(ss, off);
    if (lane == 0) sq[row] = ss;
}

// ---------------- kernel 2: row-strip fused GEMM + dist write + loss ----------------
// Block bid = (sp, ph): strips rows 4sp.. and 4(1023-sp).. x half the 16-col tiles.
// (mu,sg) rows for the block's 8 rows staged in 32 KB LDS (8 distinct y[i]).
// A-fragment pad rows 8..15 DUPLICATE rows 0..7 -> q=0,1 lanes own tile T0's
// 8 valid rows, q=2,3 lanes own tile T1's (their own a1 registers; no shfl).
// Band logic is branchless (skip-sentinel logits); noise prefetched 1 iter ahead.
__launch_bounds__(256, 4)
__global__ void fused_kernel(const unsigned short* __restrict__ xbf,
                             const float* __restrict__ sq,
                             const float* __restrict__ noise,
                             const int* __restrict__ y,
                             const float* __restrict__ meant,
                             const float* __restrict__ stdt,
                             float* __restrict__ out,
                             float* __restrict__ partials) {
    const int bid = blockIdx.x;        // 0..1023
    const int sp  = bid >> 1;          // strip pair 0..511
    const int ph  = bid & 1;           // column phase
    const int tid = threadIdx.x;
    const int wave = tid >> 6;
    const int lane = tid & 63;
    const int q   = lane >> 4;         // 0..3
    const int l16 = lane & 15;
    const int tsel = q >> 1;           // 0: tile T0, 1: tile T1
    const int rowA0 = sp * 4;
    const int rowB0 = (1023 - sp) * 4;

    // ---- stage (mu,sg) rows for the block's 8 rows into LDS ----
    __shared__ float2 musg[8][NCLS];   // 32 KB
    #pragma unroll
    for (int r = 0; r < 8; ++r) {
        const int gi = (r < 4) ? (rowA0 + r) : (rowB0 + r - 4);
        const int yr = y[gi];
        for (int c = tid; c < NCLS; c += 256)
            musg[r][c] = make_float2(meant[yr * NCLS + c], stdt[yr * NCLS + c]);
    }
    __syncthreads();

    // ---- A fragment: 16 rows = stripA(4) + stripB(4) + duplicate pad(8) ----
    const int arow = (l16 < 4) ? (rowA0 + l16)
                   : (l16 < 8) ? (rowB0 + l16 - 4)
                               : ((l16 & 4) ? (rowB0 + (l16 & 3)) : (rowA0 + (l16 & 3)));
    bf16x8 afr[4];
    #pragma unroll
    for (int kk = 0; kk < 4; ++kk)
        afr[kk] = *(const bf16x8*)(xbf + arow * DFEAT + kk * 32 + q * 8);

    // per-lane epilogue rows: C row m = q*4+t -> strips by (q&1), dup by (q>>1)
    const int ibase = (q & 1) ? rowB0 : rowA0;
    const int mbase = (q & 1) * 4;
    const f32x4 sqi = *(const f32x4*)(sq + ibase);

    size_t roff[4];                    // row byte-offset base (floats) for noise/out
    #pragma unroll
    for (int t = 0; t < 4; ++t) roff[t] = (size_t)(ibase + t) * B;

    // st: [0..2]=n1(m,sw,swd) [3..5]=n2 [6..8]=n3 [9..11]=(ps,ps2,cnt)
    float st[12];
    st[0] = st[3] = st[6] = NEG_INF_F;
    st[1] = st[2] = st[4] = st[5] = st[7] = st[8] = st[9] = st[10] = st[11] = 0.f;

    int T0 = ph + 2 * wave;            // tile pair (T0, T0+8); advances +16/iter
    int cj = (T0 + (tsel ? 8 : 0)) * 16 + l16;

    // prefetch iter-0 noise
    float nzc[4];
    #pragma unroll
    for (int t = 0; t < 4; ++t)
        nzc[t] = (cj > ibase + t) ? noise[roff[t] + cj] : 0.f;

    #pragma unroll 2
    for (int vi = 0; vi < 16; ++vi) {
        const int j0a = T0 * 16, j0b = j0a + 128;
        bf16x8 b0[4], b1[4];
        #pragma unroll
        for (int kk = 0; kk < 4; ++kk) {
            b0[kk] = *(const bf16x8*)(xbf + (j0a + l16) * DFEAT + kk * 32 + q * 8);
            b1[kk] = *(const bf16x8*)(xbf + (j0b + l16) * DFEAT + kk * 32 + q * 8);
        }

        // prefetch NEXT iteration's noise (address is index-derived, no dependence)
        const int cjn = (vi < 15) ? cj + 256 : cj;
        float nzn[4];
        #pragma unroll
        for (int t = 0; t < 4; ++t)
            nzn[t] = (cjn > ibase + t) ? noise[roff[t] + cjn] : 0.f;

        f32x4 a0 = (f32x4){0.f, 0.f, 0.f, 0.f};
        f32x4 a1 = (f32x4){0.f, 0.f, 0.f, 0.f};
        #pragma unroll
        for (int kk = 0; kk < 4; ++kk) {
            a0 = __builtin_amdgcn_mfma_f32_16x16x32_bf16(afr[kk], b0[kk], a0, 0, 0, 0);
            a1 = __builtin_amdgcn_mfma_f32_16x16x32_bf16(afr[kk], b1[kk], a1, 0, 0, 0);
        }

        const float sqc = sq[cj];
        const int yj = y[cj];
        float2 ms[4];
        #pragma unroll
        for (int t = 0; t < 4; ++t) ms[t] = musg[mbase + t][yj];

        #pragma unroll
        for (int t = 0; t < 4; ++t) {
            const int i_t = ibase + t;
            const float av = tsel ? a1[t] : a0[t];
            const float d = fmaf(-2.0f, av, sqi[t] + sqc);
            out[roff[t] + cj] = d;

            const bool valid = cj > i_t;
            const bool grp = ((i_t ^ cj) >> 3) == 0;
            const float mu = ms[t].x, sg = ms[t].y, nz = nzc[t];
            const float obs = fmaf(sg, nz, mu);
            const float t1 = fmaf(-2.5f, sg, obs);
            const float tm = fmaf(-1.5f, sg, obs);
            const float th = fmaf(1.5f, sg, obs);
            const bool nv = valid && !grp;
            const float l1 = (nv && (d < t1))               ? 10.f * (t1 - d) : SKIP_F;
            const float l2 = (nv && (d > t1) && (d < tm))   ?  5.f * (tm - d) : SKIP_F;
            const float l3 = (nv && (d > tm) && (d < th))   ?  5.f * (th - d) : SKIP_F;
            oupd(l1, d, st[0], st[1], st[2]);
            oupd(l2, d, st[3], st[4], st[5]);
            oupd(l3, d, st[6], st[7], st[8]);
            if (valid && grp) {        // positives: rare (same group of 8 only)
                const float tp = fmaf(2.0f, sg, obs);
                if (d > tp) { st[9] += d; st[10] = fmaf(d, d, st[10]); st[11] += 1.0f; }
            }
        }

        #pragma unroll
        for (int t = 0; t < 4; ++t) nzc[t] = nzn[t];
        cj = cjn;
        T0 += 16;
    }

    wave_reduce12(st);

    __shared__ float red[4][12];
    if (lane == 0) {
        #pragma unroll
        for (int k = 0; k < 12; ++k) red[wave][k] = st[k];
    }
    __syncthreads();
    if (tid == 0) {
        float r0[12];
        #pragma unroll
        for (int k = 0; k < 12; ++k) r0[k] = red[0][k];
        #pragma unroll
        for (int w = 1; w < 4; ++w) {
            omerge(r0[0], r0[1], r0[2], red[w][0], red[w][1], red[w][2]);
            omerge(r0[3], r0[4], r0[5], red[w][3], red[w][4], red[w][5]);
            omerge(r0[6], r0[7], r0[8], red[w][6], red[w][7], red[w][8]);
            r0[9] += red[w][9]; r0[10] += red[w][10]; r0[11] += red[w][11];
        }
        float* pp = partials + bid * 12;
        #pragma unroll
        for (int k = 0; k < 12; ++k) pp[k] = r0[k];
    }
}

// ---------------- kernel 3: final reduction + loss ----------------
__global__ void finalize_kernel(const float* __restrict__ partials,
                                float* __restrict__ out) {
    int tid = threadIdx.x;  // 256
    int lane = tid & 63, wave = tid >> 6;
    float st[12];
    st[0] = st[3] = st[6] = NEG_INF_F;
    st[1] = st[2] = st[4] = st[5] = st[7] = st[8] = st[9] = st[10] = st[11] = 0.f;
    for (int p = tid; p < 1024; p += 256) {
        const float* pp = partials + p * 12;
        omerge(st[0], st[1], st[2], pp[0], pp[1], pp[2]);
        omerge(st[3], st[4], st[5], pp[3], pp[4], pp[5]);
        omerge(st[6], st[7], st[8], pp[6], pp[7], pp[8]);
        st[9] += pp[9]; st[10] += pp[10]; st[11] += pp[11];
    }
    wave_reduce12(st);
    __shared__ float red[4][12];
    if (lane == 0) {
        #pragma unroll
        for (int k = 0; k < 12; ++k) red[wave][k] = st[k];
    }
    __syncthreads();
    if (tid == 0) {
        float r0[12];
        #pragma unroll
        for (int k = 0; k < 12; ++k) r0[k] = red[0][k];
        #pragma unroll
        for (int w = 1; w < 4; ++w) {
            omerge(r0[0], r0[1], r0[2], red[w][0], red[w][1], red[w][2]);
            omerge(r0[3], r0[4], r0[5], red[w][3], red[w][4], red[w][5]);
            omerge(r0[6], r0[7], r0[8], red[w][6], red[w][7], red[w][8]);
            r0[9] += red[w][9]; r0[10] += red[w][10]; r0[11] += red[w][11];
        }
        float ln1 = (r0[1] > 0.f) ? -(r0[2] / r0[1]) : -0.0001f;
        float ln2 = (r0[4] > 0.f) ? -(r0[5] / r0[4]) : -0.0001f;
        float ln3 = (r0[7] > 0.f) ? -(r0[8] / r0[7]) : -0.0001f;
        float lp  = (r0[11] > 0.f) ? (r0[10] / ((r0[9] != 0.f) ? r0[9] : 1.f)) : 0.0001f;
        out[(size_t)B * B] = 1.0f + 0.25f * (ln1 + ln2 + ln3 + lp);
    }
}

extern "C" void kernel_launch(void* const* d_in, const int* in_sizes, int n_in,
                              void* d_out, int out_size, void* d_ws, size_t ws_size,
                              hipStream_t stream) {
    const float* x     = (const float*)d_in[0];
    const int*   y     = (const int*)d_in[1];
    const float* meant = (const float*)d_in[2];
    const float* stdt  = (const float*)d_in[3];
    const float* noise = (const float*)d_in[4];
    float* out = (float*)d_out;
    char* ws = (char*)d_ws;
    unsigned short* xbf = (unsigned short*)ws;            // 1 MiB
    float* sq           = (float*)(ws + 1048576);         // 16 KiB
    float* partials     = (float*)(ws + 1064960);         // 1024*12*4 = 48 KiB

    hipLaunchKernelGGL(prep_kernel, dim3(B), dim3(64), 0, stream,
                       x, (unsigned int*)xbf, sq);
    hipLaunchKernelGGL(fused_kernel, dim3(1024), dim3(256), 0, stream,
                       xbf, sq, noise, y, meant, stdt, out, partials);
    hipLaunchKernelGGL(finalize_kernel, dim3(1), dim3(256), 0, stream,
                       partials, out);
}

// Round 7
// 168.879 us; speedup vs baseline: 1.5547x; 1.1921x over previous
//
#include <hip/hip_runtime.h>
#include <hip/hip_bf16.h>

#define B 4096
#define DFEAT 128
#define NCLS 512
#define NEG_INF_F (-1e30f)
// log2-domain temps: TEMP*log2(e), (TEMP-5)*log2(e) — weights 2^(k*logit) give
// identical softmax ratios; all exps below are exp2 (v_exp_f32 is natively exp2).
#define T1_L2 14.426950408889634f
#define T2_L2 7.213475204444817f

typedef __attribute__((ext_vector_type(8))) short bf16x8;
typedef __attribute__((ext_vector_type(4))) float f32x4;

__device__ __forceinline__ unsigned short f2bf(float f) {
    unsigned int u = __float_as_uint(f);
    unsigned int r = (u + 0x7fffu + ((u >> 16) & 1u)) >> 16;
    return (unsigned short)r;
}

// online softmax-weighted accumulation (log2-domain logits): add entry, value d
__device__ __forceinline__ void oupd(float logit, float d, float& m, float& sw, float& swd) {
    if (logit > m) {
        float e = exp2f(m - logit);   // m==-1e30 -> e==0 -> resets cleanly
        sw  = fmaf(sw, e, 1.0f);
        swd = fmaf(swd, e, d);
        m = logit;
    } else {
        float e = exp2f(logit - m);
        sw += e;
        swd = fmaf(e, d, swd);
    }
}

__device__ __forceinline__ void omerge(float& m, float& sw, float& swd,
                                       float m2, float sw2, float swd2) {
    float M = fmaxf(m, m2);
    float e1 = exp2f(m - M);
    float e2 = exp2f(m2 - M);
    sw  = sw * e1 + sw2 * e2;
    swd = swd * e1 + swd2 * e2;
    m = M;
}

// reference band logic for a strictly-upper negative pair (log2-domain temps)
__device__ __forceinline__ void neg_update(float d, float mu, float sg, float nz, float st[12]) {
    float obs = fmaf(sg, nz, mu);
    float t1 = fmaf(-2.5f, sg, obs);
    if (d < t1) {
        oupd(T1_L2 * (t1 - d), d, st[0], st[1], st[2]);
    } else {
        float tm = fmaf(-1.5f, sg, obs);
        if (d < tm) {
            if (d > t1) oupd(T2_L2 * (tm - d), d, st[3], st[4], st[5]);
        } else {
            float th = fmaf(1.5f, sg, obs);
            if (d < th && d > tm) oupd(T2_L2 * (th - d), d, st[6], st[7], st[8]);
        }
    }
}

__device__ __forceinline__ void wave_reduce12(float st[12]) {
    #pragma unroll
    for (int off = 32; off; off >>= 1) {
        float o[12];
        #pragma unroll
        for (int k = 0; k < 12; ++k) o[k] = __shfl_down(st[k], off);
        omerge(st[0], st[1], st[2], o[0], o[1], o[2]);
        omerge(st[3], st[4], st[5], o[3], o[4], o[5]);
        omerge(st[6], st[7], st[8], o[6], o[7], o[8]);
        st[9] += o[9]; st[10] += o[10]; st[11] += o[11];
    }
}

// ---------------- kernel 1: x -> bf16 copy + row sum-of-squares ----------------
__global__ void prep_kernel(const float* __restrict__ x,
                            unsigned int* __restrict__ xbf_packed,
                            float* __restrict__ sq) {
    int row = blockIdx.x;
    int lane = threadIdx.x;  // 64
    float2 v = ((const float2*)(x + row * DFEAT))[lane];
    float ss = fmaf(v.x, v.x, v.y * v.y);
    unsigned int pk = ((unsigned int)f2bf(v.y) << 16) | (unsigned int)f2bf(v.x);
    xbf_packed[row * (DFEAT / 2) + lane] = pk;
    #pragma unroll
    for (int off = 32; off; off >>= 1) ss += __shfl_down(ss, off);
    if (lane == 0) sq[row] = ss;
}

// ---------------- kernel 2: pure GEMM -> dist write ----------------
__launch_bounds__(256)
__global__ void dist_kernel(const unsigned short* __restrict__ xbf,
                            const float* __restrict__ sq,
                            float* __restrict__ out) {
    const int bx = blockIdx.x;       // col tile
    const int by = blockIdx.y;       // row tile
    const int tid = threadIdx.x;
    const int wave = tid >> 6;
    const int lane = tid & 63;
    const int q = lane >> 4;         // 0..3
    const int l16 = lane & 15;
    const int row0 = by * 128 + (wave >> 1) * 64;
    const int col0 = bx * 128 + (wave & 1) * 64;

    f32x4 acc[4][4];
    #pragma unroll
    for (int r = 0; r < 4; ++r)
        #pragma unroll
        for (int c = 0; c < 4; ++c)
            acc[r][c] = (f32x4){0.f, 0.f, 0.f, 0.f};

    #pragma unroll
    for (int kk = 0; kk < 4; ++kk) {
        const int ko = kk * 32 + q * 8;
        bf16x8 afr[4], bfr[4];
        #pragma unroll
        for (int r = 0; r < 4; ++r)
            afr[r] = *(const bf16x8*)(xbf + (row0 + r * 16 + l16) * DFEAT + ko);
        #pragma unroll
        for (int c = 0; c < 4; ++c)
            bfr[c] = *(const bf16x8*)(xbf + (col0 + c * 16 + l16) * DFEAT + ko);
        #pragma unroll
        for (int r = 0; r < 4; ++r)
            #pragma unroll
            for (int c = 0; c < 4; ++c)
                acc[r][c] = __builtin_amdgcn_mfma_f32_16x16x32_bf16(afr[r], bfr[c], acc[r][c], 0, 0, 0);
    }

    float sqr[4][4];
    #pragma unroll
    for (int r = 0; r < 4; ++r)
        *(f32x4*)sqr[r] = *(const f32x4*)(sq + row0 + r * 16 + q * 4);
    int cols[4]; float sqc[4];
    #pragma unroll
    for (int c = 0; c < 4; ++c) {
        cols[c] = col0 + c * 16 + l16;
        sqc[c] = sq[cols[c]];
    }

    #pragma unroll
    for (int r = 0; r < 4; ++r) {
        #pragma unroll
        for (int t = 0; t < 4; ++t) {
            int base = (row0 + r * 16 + q * 4 + t) * B;
            float s = sqr[r][t];
            #pragma unroll
            for (int c = 0; c < 4; ++c)
                out[base + cols[c]] = fmaf(-2.0f, acc[r][c][t], s + sqc[c]);
        }
    }
}

// ---------------- kernel 3: streaming upper-triangle loss ----------------
// block b handles rows i=b and j=B-1-b (balanced).
// positives for row r are exactly cols r+1..(r|7)  (<=7, scalar head);
// negatives are cols (r|7)+1..B-1 (8-aligned start -> float4 body, branch-free).
__device__ __forceinline__ void process_row(int row,
                                            const float* __restrict__ drow,
                                            const float* __restrict__ nrow,
                                            const int* __restrict__ y,
                                            const float* __restrict__ muS,
                                            const float* __restrict__ sgS,
                                            int tid, float st[12]) {
    const int ge = row | 7;
    const int npos = ge - row;         // 0..7
    if (tid < npos) {
        int col = row + 1 + tid;
        float d = drow[col], nz = nrow[col];
        int yc = y[col];
        float sg = sgS[yc];
        float obs = fmaf(sg, nz, muS[yc]);
        float tp = fmaf(2.0f, sg, obs);
        if (d > tp) { st[9] += d; st[10] = fmaf(d, d, st[10]); st[11] += 1.0f; }
    }
    for (int col = ge + 1 + tid * 4; col < B; col += 1024) {
        float4 d4 = *(const float4*)(drow + col);
        float4 n4 = *(const float4*)(nrow + col);
        int4  y4 = *(const int4*)(y + col);
        neg_update(d4.x, muS[y4.x], sgS[y4.x], n4.x, st);
        neg_update(d4.y, muS[y4.y], sgS[y4.y], n4.y, st);
        neg_update(d4.z, muS[y4.z], sgS[y4.z], n4.z, st);
        neg_update(d4.w, muS[y4.w], sgS[y4.w], n4.w, st);
    }
}

__launch_bounds__(256)
__global__ void loss_kernel(const float* __restrict__ dist,
                            const float* __restrict__ noise,
                            const int* __restrict__ y,
                            const float* __restrict__ meant,
                            const float* __restrict__ stdt,
                            float* __restrict__ partials) {
    const int b = blockIdx.x;       // 0..2047
    const int i = b;
    const int j = B - 1 - b;
    const int tid = threadIdx.x;
    const int lane = tid & 63, wave = tid >> 6;

    __shared__ float mu0[NCLS], sg0[NCLS], mu1[NCLS], sg1[NCLS];
    const int yi = y[i], yj = y[j];
    for (int c = tid * 4; c < NCLS; c += 1024) {
        *(float4*)(mu0 + c) = *(const float4*)(meant + yi * NCLS + c);
        *(float4*)(sg0 + c) = *(const float4*)(stdt  + yi * NCLS + c);
        *(float4*)(mu1 + c) = *(const float4*)(meant + yj * NCLS + c);
        *(float4*)(sg1 + c) = *(const float4*)(stdt  + yj * NCLS + c);
    }
    __syncthreads();

    // st: [0..2]=n1(m,sw,swd) [3..5]=n2 [6..8]=n3 [9..11]=(ps,ps2,cnt)
    float st[12];
    st[0] = st[3] = st[6] = NEG_INF_F;
    st[1] = st[2] = st[4] = st[5] = st[7] = st[8] = st[9] = st[10] = st[11] = 0.f;

    process_row(i, dist + (size_t)i * B, noise + (size_t)i * B, y, mu0, sg0, tid, st);
    process_row(j, dist + (size_t)j * B, noise + (size_t)j * B, y, mu1, sg1, tid, st);

    wave_reduce12(st);

    __shared__ float red[4][12];
    if (lane == 0) {
        #pragma unroll
        for (int k = 0; k < 12; ++k) red[wave][k] = st[k];
    }
    __syncthreads();
    if (tid == 0) {
        float r0[12];
        #pragma unroll
        for (int k = 0; k < 12; ++k) r0[k] = red[0][k];
        #pragma unroll
        for (int w = 1; w < 4; ++w) {
            omerge(r0[0], r0[1], r0[2], red[w][0], red[w][1], red[w][2]);
            omerge(r0[3], r0[4], r0[5], red[w][3], red[w][4], red[w][5]);
            omerge(r0[6], r0[7], r0[8], red[w][6], red[w][7], red[w][8]);
            r0[9] += red[w][9]; r0[10] += red[w][10]; r0[11] += red[w][11];
        }
        float* pp = partials + b * 12;
        #pragma unroll
        for (int k = 0; k < 12; ++k) pp[k] = r0[k];
    }
}

// ---------------- kernel 4: final reduction + loss ----------------
__global__ void finalize_kernel(const float* __restrict__ partials,
                                float* __restrict__ out) {
    int tid = threadIdx.x;  // 256
    int lane = tid & 63, wave = tid >> 6;
    float st[12];
    st[0] = st[3] = st[6] = NEG_INF_F;
    st[1] = st[2] = st[4] = st[5] = st[7] = st[8] = st[9] = st[10] = st[11] = 0.f;
    for (int p = tid; p < 2048; p += 256) {
        const float* pp = partials + p * 12;
        omerge(st[0], st[1], st[2], pp[0], pp[1], pp[2]);
        omerge(st[3], st[4], st[5], pp[3], pp[4], pp[5]);
        omerge(st[6], st[7], st[8], pp[6], pp[7], pp[8]);
        st[9] += pp[9]; st[10] += pp[10]; st[11] += pp[11];
    }
    wave_reduce12(st);
    __shared__ float red[4][12];
    if (lane == 0) {
        #pragma unroll
        for (int k = 0; k < 12; ++k) red[wave][k] = st[k];
    }
    __syncthreads();
    if (tid == 0) {
        float r0[12];
        #pragma unroll
        for (int k = 0; k < 12; ++k) r0[k] = red[0][k];
        #pragma unroll
        for (int w = 1; w < 4; ++w) {
            omerge(r0[0], r0[1], r0[2], red[w][0], red[w][1], red[w][2]);
            omerge(r0[3], r0[4], r0[5], red[w][3], red[w][4], red[w][5]);
            omerge(r0[6], r0[7], r0[8], red[w][6], red[w][7], red[w][8]);
            r0[9] += red[w][9]; r0[10] += red[w][10]; r0[11] += red[w][11];
        }
        float ln1 = (r0[1] > 0.f) ? -(r0[2] / r0[1]) : -0.0001f;
        float ln2 = (r0[4] > 0.f) ? -(r0[5] / r0[4]) : -0.0001f;
        float ln3 = (r0[7] > 0.f) ? -(r0[8] / r0[7]) : -0.0001f;
        float lp  = (r0[11] > 0.f) ? (r0[10] / ((r0[9] != 0.f) ? r0[9] : 1.f)) : 0.0001f;
        out[(size_t)B * B] = 1.0f + 0.25f * (ln1 + ln2 + ln3 + lp);
    }
}

extern "C" void kernel_launch(void* const* d_in, const int* in_sizes, int n_in,
                              void* d_out, int out_size, void* d_ws, size_t ws_size,
                              hipStream_t stream) {
    const float* x     = (const float*)d_in[0];
    const int*   y     = (const int*)d_in[1];
    const float* meant = (const float*)d_in[2];
    const float* stdt  = (const float*)d_in[3];
    const float* noise = (const float*)d_in[4];
    float* out = (float*)d_out;
    char* ws = (char*)d_ws;
    unsigned short* xbf = (unsigned short*)ws;            // 1 MiB
    float* sq           = (float*)(ws + 1048576);         // 16 KiB
    float* partials     = (float*)(ws + 1064960);         // 2048*12*4 = 96 KiB

    hipLaunchKernelGGL(prep_kernel, dim3(B), dim3(64), 0, stream,
                       x, (unsigned int*)xbf, sq);
    hipLaunchKernelGGL(dist_kernel, dim3(32, 32), dim3(256), 0, stream,
                       xbf, sq, out);
    hipLaunchKernelGGL(loss_kernel, dim3(2048), dim3(256), 0, stream,
                       out, noise, y, meant, stdt, partials);
    hipLaunchKernelGGL(finalize_kernel, dim3(1), dim3(256), 0, stream,
                       partials, out);
}